// Round 7
// baseline (7327.106 us; speedup 1.0000x reference)
//
#include <hip/hip_runtime.h>
#include <math.h>

// ---------------- problem constants ----------------
#define B_    16
#define S_    512
#define IN_   258
#define ST_   512
#define RD_   128
#define UPD_  404
#define COLS_ 916
#define CPAD_ 920
#define G_MM  10           // blocks per batch; each holds a full memory-module replica
#define CPB_  92
#define ROLES_ G_MM

typedef unsigned long long u64t;

// ---------------- workspace layout ----------------
#define XPART_F  (8192*CPAD_)                 // floats
#define STTAG_N  ((size_t)B_*513*512)         // u64 {state val, tag}
#define RDTAG_N  ((size_t)B_*513*128)         // u64 {read val, tag} (outgemm only)
#define UPTAG_N  ((size_t)B_*2*512)           // u64 {upd val, tag}, double-buffered
#define TAGS_N   (STTAG_N + RDTAG_N + UPTAG_N)

// Relaxed agent-scope 8B atomics: single global_load/store_dwordx2 sc0 sc1
// (LLC-direct, bypass non-coherent L1/L2, truly atomic at 8B).
#define AT_LD64(p)   __hip_atomic_load((p), __ATOMIC_RELAXED, __HIP_MEMORY_SCOPE_AGENT)
#define AT_ST64(p,v) __hip_atomic_store((p), (v), __ATOMIC_RELAXED, __HIP_MEMORY_SCOPE_AGENT)

union VT { u64t u; struct { float v; int t; } s; };
__device__ __forceinline__ u64t packVT(float v, int t){ VT x; x.s.v=v; x.s.t=t; return x.u; }
__device__ __forceinline__ float vtVal(u64t u){ VT x; x.u=u; return x.s.v; }
__device__ __forceinline__ int   vtTag(u64t u){ VT x; x.u=u; return x.s.t; }
__host__ __device__ __forceinline__ float vtValH(u64t u){ VT x; x.u=u; return x.s.v; }

// fused flag+data poll: ONE LLC round trip delivers readiness AND the value
__device__ __forceinline__ float pollVal(const u64t* p, int want){
  u64t v = AT_LD64(p);
  int c=0;
  while (vtTag(v) != want){
    __builtin_amdgcn_s_sleep(1);
    v = AT_LD64(p);
    if (++c > (1<<22)) break;   // safety bail: wrong output rather than hang
  }
  return vtVal(v);
}

// LDS: matmul staging + memory-module replica. 153,856 B < 160 KiB.
// mem pad 513 (stride 513%32==1): conflict-free for BOTH row- and col-threaded
// scalar passes. wt/dyn/wscr interleaved [n][2] for b64 broadcast/pair reads.
struct Smem {
  float mem[64*513];
  float wtl[512*2];
  float dynl[512*2];
  float wscrl[512*2];
  float comb[640];          // [state(512) | read(128)]
  float part[5][CPB_];
  float kn[2][64];
  float es[2][64];
  float ad[2][64];
  float rp2[8*64*2];        // float2 per (g,m): {r_h0, r_h1}
  float redE[16];
  float redG[16];
  float upraw[20];          // raw scalars: h0[0..7], h1[8..15], beta/g pairs [16..19]
};

__device__ __forceinline__ float sigm(float x){ return 1.f/(1.f+__expf(-x)); }
__device__ __forceinline__ float splus(float x){ return fmaxf(x,0.f)+log1pf(__expf(-fabsf(x))); }

// P2: erase/add memory update fused with read(tnext); read -> comb[512..] (local).
// wtl handoff from P1 is wave-local (wave g owns cols [g*64, g*64+64) in both
// phases) -> no barrier before entry; one barrier (H) for the rp2 reduction.
__device__ __forceinline__ void p2_step(Smem& S, int bb, int tnext, bool pubRd,
                                        u64t* __restrict__ rdTag, int tid)
{
  const int m = tid & 63, g = tid >> 6;
  const float e0=S.es[0][m], e1=S.es[1][m], a0=S.ad[0][m], a1=S.ad[1][m];
  float r0=0.f, r1=0.f;
  const int base = m*513 + g*64;
  const float2* wt2 = (const float2*)S.wtl;
  #pragma unroll 8
  for (int kk=0; kk<64; ++kk){
    float2 w = wt2[g*64+kk];            // broadcast read (all lanes same addr)
    float v = S.mem[base+kk];
    float E = fmaf(e0, w.x, e1*w.y);
    float A = fmaf(a0, w.x, a1*w.y);
    v = fmaf(v, -E, v) + A;             // v*(1-E)+A
    S.mem[base+kk] = v;
    r0 = fmaf(w.x, v, r0);
    r1 = fmaf(w.y, v, r1);
  }
  ((float2*)S.rp2)[g*64+m] = make_float2(r0, r1);
  __syncthreads();                      // H: rp2 cross-wave
  if (tid < 128){
    int h = tid>>6, mm = tid&63;
    float s = 0.f;
    #pragma unroll
    for (int gg=0; gg<8; ++gg){
      float2 p = ((const float2*)S.rp2)[gg*64+mm];
      s += h ? p.y : p.x;
    }
    S.comb[512+tid] = s;                // read(tnext) stays LOCAL
    if (pubRd)
      AT_ST64(&rdTag[((size_t)(bb*513+tnext))*RD_+tid], packVT(s, tnext+1));
  }
  // no trailing barrier: loop-top barrier A covers comb visibility
}

// ---------------- init: zero all tag words; state(0)=ones tag=1 ----------------
__global__ void init_kernel(u64t* __restrict__ stTag, u64t* __restrict__ rdTag,
                            u64t* __restrict__ upTag)
{
  size_t i = (size_t)blockIdx.x*blockDim.x + threadIdx.x;
  if (i < STTAG_N) {
    size_t rem = i % (513*512);
    int t = (int)(rem >> 9);
    stTag[i] = (t==0) ? packVT(1.f, 1) : 0ULL;
  } else if (i < STTAG_N + RDTAG_N) {
    rdTag[i - STTAG_N] = 0ULL;
  } else if (i < TAGS_N) {
    upTag[i - STTAG_N - RDTAG_N] = 0ULL;
  }
}

// ---------------- xpart = X @ W[0:258, state|upd] + bias ----------------
__global__ __launch_bounds__(256) void xpart_kernel(const float* __restrict__ X,
    const float* __restrict__ Ws, const float* __restrict__ Wu,
    const float* __restrict__ bs, const float* __restrict__ bu,
    float* __restrict__ xpart)
{
  __shared__ float Xs[32][65];
  __shared__ float Wsh[32][65];
  const int row0=blockIdx.x*64, c0=blockIdx.y*64;
  const int tid=threadIdx.x, tx=tid&15, ty=tid>>4;
  float acc[4][4]={};
  for(int k0=0;k0<IN_;k0+=32){
    for(int i=tid;i<32*64;i+=256){
      int kk=i&31, tt=i>>5, k=k0+kk;
      Xs[kk][tt]=(k<IN_)?X[(size_t)(row0+tt)*IN_+k]:0.f;
    }
    for(int i=tid;i<32*64;i+=256){
      int cc=i&63, kk=i>>6, k=k0+kk, c=c0+cc;
      float v=0.f;
      if(k<IN_){
        if(c<512) v=Ws[(size_t)k*512+c];
        else if(c<COLS_) v=Wu[(size_t)k*404+(c-512)];
      }
      Wsh[kk][cc]=v;
    }
    __syncthreads();
    #pragma unroll
    for(int kk=0;kk<32;kk++){
      float xv[4],wv[4];
      #pragma unroll
      for(int i=0;i<4;i++) xv[i]=Xs[kk][ty*4+i];
      #pragma unroll
      for(int j=0;j<4;j++) wv[j]=Wsh[kk][tx*4+j];
      #pragma unroll
      for(int i=0;i<4;i++)
        #pragma unroll
        for(int j=0;j<4;j++) acc[i][j]=fmaf(xv[i],wv[j],acc[i][j]);
    }
    __syncthreads();
  }
  #pragma unroll
  for(int i=0;i<4;i++){
    int r=row0+ty*4+i;
    #pragma unroll
    for(int j=0;j<4;j++){
      int c=c0+tx*4+j;
      if(c<COLS_){
        float bias=(c<512)?bs[c]:bu[c-512];
        xpart[(size_t)r*CPAD_+c]=acc[i][j]+bias;
      }
    }
  }
}

// ---------------- deferred output GEMM: out = sigmoid([x,state,read]@Wo + bo) ----------------
__global__ __launch_bounds__(256) void outgemm_kernel(const float* __restrict__ X,
    const u64t* __restrict__ stTag, const u64t* __restrict__ rdTag,
    const float* __restrict__ Wo, const float* __restrict__ bo, float* __restrict__ out)
{
  __shared__ float Cs[32][65];
  __shared__ float Wsh[32][65];
  const int row0=blockIdx.x*64, c0=blockIdx.y*64;
  const int tid=threadIdx.x, tx=tid&15, ty=tid>>4;
  float acc[4][4]={};
  for(int k0=0;k0<898;k0+=32){
    for(int i=tid;i<32*64;i+=256){
      int kk=i&31, tt=i>>5, k=k0+kk, row=row0+tt;
      float v=0.f;
      if(k<258) v=X[(size_t)row*IN_+k];
      else if(k<770){ int b=row>>9,t=row&511; v=vtValH(stTag[((size_t)(b*513+t))*512+(k-258)]); }
      else if(k<898){ int b=row>>9,t=row&511; v=vtValH(rdTag[((size_t)(b*513+t))*128+(k-770)]); }
      Cs[kk][tt]=v;
    }
    for(int i=tid;i<32*64;i+=256){
      int cc=i&63, kk=i>>6, k=k0+kk;
      Wsh[kk][cc]=(k<898)?Wo[(size_t)k*256+(c0+cc)]:0.f;
    }
    __syncthreads();
    #pragma unroll
    for(int kk=0;kk<32;kk++){
      float xv[4],wv[4];
      #pragma unroll
      for(int i=0;i<4;i++) xv[i]=Cs[kk][ty*4+i];
      #pragma unroll
      for(int j=0;j<4;j++) wv[j]=Wsh[kk][tx*4+j];
      #pragma unroll
      for(int i=0;i<4;i++)
        #pragma unroll
        for(int j=0;j<4;j++) acc[i][j]=fmaf(xv[i],wv[j],acc[i][j]);
    }
    __syncthreads();
  }
  #pragma unroll
  for(int i=0;i<4;i++){
    int r=row0+ty*4+i;
    #pragma unroll
    for(int j=0;j<4;j++){
      int c=c0+tx*4+j;
      out[(size_t)r*256+c]=sigm(acc[i][j]+bo[c]);
    }
  }
}

// ---------------- main persistent recurrent kernel ----------------
// 10 blocks per batch; each: 92-col slice of the controller matmul AND a full
// memory-module replica. ONE inter-block hop per step (state/upd broadcast).
// 7 barriers/step; upd transforms + colNorm overlapped with the hop.
__global__ __launch_bounds__(512, 1) void main_kernel(
    const float* __restrict__ Ws, const float* __restrict__ Wu,
    const float* __restrict__ xpart, u64t* __restrict__ stTag,
    u64t* __restrict__ rdTag, u64t* __restrict__ upTag)
{
  extern __shared__ char smem[];
  Smem& S = *(Smem*)smem;
  const int bb   = blockIdx.x & 15;
  const int role = blockIdx.x >> 4;
  const int tid  = threadIdx.x;

  // -------- weight slice in registers (full unroll -> register resident) ----
  const int c  = tid % CPB_;
  const int rc = tid / CPB_;             // 0..3 state chunks, 4 read chunk, 5 idle
  const int cg = role*CPB_ + c;
  const bool cvalid = (cg < COLS_);
  const float* Wp; int ldw, ci;
  if (cg < 512) { Wp = Ws; ldw = 512; ci = cg; }
  else          { Wp = Wu; ldw = 404; ci = cvalid ? (cg-512) : 0; }
  float wreg[128];
  if (rc < 5) {
    #pragma unroll
    for (int j = 0; j < 128; ++j)
      wreg[j] = Wp[(size_t)(258 + rc*128 + j)*ldw + ci];
  }

  // -------- memory-module replica init --------
  for (int i = tid; i < 64*513; i += 512) S.mem[i] = 0.01f;
  {
    float o0 = (tid == 0) ? 1.f : 0.f;
    ((float2*)S.wtl)[tid]  = make_float2(o0, o0);
    ((float2*)S.dynl)[tid] = make_float2(o0, o0);
  }
  if (tid < 128) { S.es[tid>>6][tid&63]=0.f; S.ad[tid>>6][tid&63]=0.f; }
  __syncthreads();
  // prologue: read(0) (zero erase/add == pure read from initial wt/mem)
  p2_step(S, bb, 0, role==0, rdTag, tid);

  for (int t = 0; t < S_-1; ++t) {
    // prefetch xpart (read-only, cached)
    float xp = 0.f;
    if (tid < CPB_ && cvalid) xp = xpart[(size_t)(bb*512 + t)*CPAD_ + cg];
    // state(t): per-element tagged poll (instant in steady state)
    S.comb[tid] = pollVal(&stTag[((size_t)(bb*513 + t))*512 + tid], t+1);
    __syncthreads();                                    // A: comb (state+read)
    if (rc < 5) {
      float acc = 0.f;
      const float4* cb = (const float4*)&S.comb[rc*128];
      #pragma unroll
      for (int j4 = 0; j4 < 32; ++j4) {
        float4 cv = cb[j4];
        acc = fmaf(cv.x, wreg[4*j4+0], acc);
        acc = fmaf(cv.y, wreg[4*j4+1], acc);
        acc = fmaf(cv.z, wreg[4*j4+2], acc);
        acc = fmaf(cv.w, wreg[4*j4+3], acc);
      }
      S.part[rc][c] = acc;
    }
    __syncthreads();                                    // B: part
    if (tid < CPB_ && cvalid) {
      float pre = xp + S.part[0][tid] + S.part[1][tid] + S.part[2][tid]
                     + S.part[3][tid] + S.part[4][tid];
      if (cg < 512)   // tagged store IS the release
        AT_ST64(&stTag[((size_t)(bb*513 + t + 1))*512 + cg], packVT(sigm(pre), t+2));
      else
        AT_ST64(&upTag[((size_t)(bb*2 + (t&1)))*512 + (cg-512)], packVT(pre, t+1));
    }
    // colNorm of current mem (wave-local LDS) — overlaps the hop
    float nrmInv;
    {
      float nrm = 0.f;
      #pragma unroll 8
      for (int m2 = 0; m2 < 64; ++m2){ float v = S.mem[m2*513 + tid]; nrm = fmaf(v,v,nrm); }
      nrmInv = 1.f/(sqrtf(nrm)+1e-12f);
    }
    // fused upd(t) poll + transform (runs during the hop wait)
    {
      const u64t* ub = &upTag[((size_t)(bb*2 + (t&1)))*512];
      if (tid < 128) {                    // keys + per-head norm (full-wave butterfly)
        int h = tid>>6, m2 = tid&63;
        float kv = pollVal(&ub[h*202 + 136 + m2], t+1);
        float s2 = kv*kv;
        #pragma unroll
        for (int o=32;o;o>>=1) s2 += __shfl_xor(s2, o);
        S.kn[h][m2] = kv/(sqrtf(s2)+1e-12f);
      } else if (tid < 256) {             // erase
        int h = (tid>>6)&1, m2 = tid&63;
        S.es[h][m2] = sigm(pollVal(&ub[h*202 + 8 + m2], t+1));
      } else if (tid < 384) {             // add
        int h = (tid>>6)&1, m2 = tid&63;
        S.ad[h][m2] = pollVal(&ub[h*202 + 72 + m2], t+1);
      } else if (tid < 400) {             // raw scalars s(3),jd,j(3),gamma per head
        int h = (tid-384)>>3, s = tid&7;
        S.upraw[h*8 + s] = pollVal(&ub[h*202 + s], t+1);
      } else if (tid < 404) {             // beta, g per head
        int h = (tid-400)>>1, s = tid&1;
        S.upraw[16 + h*2 + s] = pollVal(&ub[h*202 + 200 + s], t+1);
      }
    }
    __syncthreads();                                    // C: upd ready
    // redundant per-thread smalls (parallel; removes a barrier + serializer)
    float sA0,sA1,sA2,sB0,sB1,sB2, jA0,jA1,jA2,jB0,jB1,jB2;
    float jd0,jd1,gam0,gam1,bet0,bet1,g0,g1;
    {
      float sp0=splus(S.upraw[0]), sp1=splus(S.upraw[1]), sp2=splus(S.upraw[2]);
      float e0=__expf(sp0), e1=__expf(sp1), e2=__expf(sp2), iv=1.f/(e0+e1+e2);
      sA0=e0*iv; sA1=e1*iv; sA2=e2*iv;
      float f0=__expf(S.upraw[4]), f1=__expf(S.upraw[5]), f2=__expf(S.upraw[6]);
      float ivj=1.f/(f0+f1+f2);
      jA0=f0*ivj; jA1=f1*ivj; jA2=f2*ivj;
      jd0=sigm(S.upraw[3]); gam0=1.f+splus(S.upraw[7]);
      bet0=splus(S.upraw[16]); g0=sigm(S.upraw[17]);
      sp0=splus(S.upraw[8]); sp1=splus(S.upraw[9]); sp2=splus(S.upraw[10]);
      e0=__expf(sp0); e1=__expf(sp1); e2=__expf(sp2); iv=1.f/(e0+e1+e2);
      sB0=e0*iv; sB1=e1*iv; sB2=e2*iv;
      f0=__expf(S.upraw[12]); f1=__expf(S.upraw[13]); f2=__expf(S.upraw[14]);
      ivj=1.f/(f0+f1+f2);
      jB0=f0*ivj; jB1=f1*ivj; jB2=f2*ivj;
      jd1=sigm(S.upraw[11]); gam1=1.f+splus(S.upraw[15]);
      bet1=splus(S.upraw[18]); g1=sigm(S.upraw[19]);
    }
    // ---- P1: cosine scores, softmax (no max-sub: score<=beta, safe), mix,
    //          shift, sharpen. Reductions: single barrier each. ----
    {
      const int n = tid;
      float d0=0.f, d1=0.f;
      #pragma unroll 8
      for (int m2=0; m2<64; ++m2){
        float v = S.mem[m2*513 + n];
        d0 = fmaf(S.kn[0][m2], v, d0);
        d1 = fmaf(S.kn[1][m2], v, d1);
      }
      float ex0 = __expf(bet0*d0*nrmInv), ex1 = __expf(bet1*d1*nrmInv);
      float sm0=ex0, sm1=ex1;
      #pragma unroll
      for (int o=32;o;o>>=1){ sm0+=__shfl_xor(sm0,o); sm1+=__shfl_xor(sm1,o); }
      if ((tid&63)==0){ S.redE[(tid>>6)*2]=sm0; S.redE[(tid>>6)*2+1]=sm1; }
      __syncthreads();                                  // E: softmax sum
      sm0=S.redE[0]; sm1=S.redE[1];
      #pragma unroll
      for (int i=1;i<8;++i){ sm0+=S.redE[2*i]; sm1+=S.redE[2*i+1]; }
      float wtk0 = ex0/sm0, wtk1 = ex1/sm1;
      float2 wo  = ((const float2*)S.wtl)[n];
      float2 dyo = ((const float2*)S.dynl)[n];
      float dn0 = fmaf(jd0, wo.x - dyo.x, dyo.x);
      float dn1 = fmaf(jd1, wo.y - dyo.y, dyo.y);
      ((float2*)S.dynl)[n] = make_float2(dn0, dn1);
      float fx = (n==0) ? 1.f : 0.f;
      float wm0 = jA0*wo.x + jA1*dn0 + jA2*fx;
      float wm1 = jB0*wo.y + jB1*dn1 + jB2*fx;
      float wc0 = fmaf(g0, wtk0-wm0, wm0);
      float wc1 = fmaf(g1, wtk1-wm1, wm1);
      ((float2*)S.wscrl)[n] = make_float2(wc0, wc1);
      __syncthreads();                                  // F: wscr (shift neighbors)
      int np=(n+1)&511, nm=(n-1)&511;
      float2 wpn = ((const float2*)S.wscrl)[np];
      float2 wmn = ((const float2*)S.wscrl)[nm];
      float wsh0 = sA0*wpn.x + sA1*wc0 + sA2*wmn.x;
      float wsh1 = sB0*wpn.y + sB1*wc1 + sB2*wmn.y;
      float q0 = (wsh0>0.f) ? __expf(gam0*__logf(wsh0)) : 0.f;
      float q1 = (wsh1>0.f) ? __expf(gam1*__logf(wsh1)) : 0.f;
      float ds0=q0, ds1=q1;
      #pragma unroll
      for (int o=32;o;o>>=1){ ds0+=__shfl_xor(ds0,o); ds1+=__shfl_xor(ds1,o); }
      if ((tid&63)==0){ S.redG[(tid>>6)*2]=ds0; S.redG[(tid>>6)*2+1]=ds1; }
      __syncthreads();                                  // G: sharpen sum
      ds0=S.redG[0]; ds1=S.redG[1];
      #pragma unroll
      for (int i=1;i<8;++i){ ds0+=S.redG[2*i]; ds1+=S.redG[2*i+1]; }
      ((float2*)S.wtl)[n] = make_float2(q0/(ds0+1e-12f), q1/(ds1+1e-12f));
    }
    // wtl handoff to P2 is wave-local; ensure LDS writes complete (in-wave)
    asm volatile("s_waitcnt lgkmcnt(0)" ::: "memory");
    __builtin_amdgcn_sched_barrier(0);
    // ---- P2: mem update + read(t+1) into comb (local) ----
    p2_step(S, bb, t+1, role==0, rdTag, tid);
  }
}

// ---------------- launch ----------------
extern "C" void kernel_launch(void* const* d_in, const int* in_sizes, int n_in,
                              void* d_out, int out_size, void* d_ws, size_t ws_size,
                              hipStream_t stream) {
  (void)in_sizes; (void)n_in; (void)out_size;
  const float* X  = (const float*)d_in[0];
  const float* Ws = (const float*)d_in[1];
  const float* bs = (const float*)d_in[2];
  const float* Wo = (const float*)d_in[3];
  const float* bo = (const float*)d_in[4];
  const float* Wu = (const float*)d_in[5];
  const float* bu = (const float*)d_in[6];
  float* out = (float*)d_out;

  const size_t needed = (size_t)XPART_F*4 + TAGS_N*8;
  if (ws_size < needed) return;   // fail visibly rather than corrupt memory

  float* xpart  = (float*)d_ws;
  u64t*  stTag  = (u64t*)(xpart + XPART_F);   // XPART_F*4 is 8B-aligned
  u64t*  rdTag  = stTag + STTAG_N;
  u64t*  upTag  = rdTag + RDTAG_N;

  hipLaunchKernelGGL(init_kernel, dim3((unsigned)((TAGS_N + 255)/256)), dim3(256), 0, stream,
                     stTag, rdTag, upTag);
  hipLaunchKernelGGL(xpart_kernel, dim3(128, 15), dim3(256), 0, stream, X, Ws, Wu, bs, bu, xpart);

  (void)hipFuncSetAttribute((const void*)main_kernel,
        hipFuncAttributeMaxDynamicSharedMemorySize, (int)sizeof(Smem));
  void* kargs[] = { (void*)&Ws, (void*)&Wu, (void*)&xpart, (void*)&stTag,
                    (void*)&rdTag, (void*)&upTag };
  hipLaunchCooperativeKernel((const void*)main_kernel, dim3(B_*ROLES_), dim3(512),
                             kargs, (unsigned)sizeof(Smem), stream);

  hipLaunchKernelGGL(outgemm_kernel, dim3(128, 4), dim3(256), 0, stream,
                     X, stTag, rdTag, Wo, bo, out);
}